// Round 3
// baseline (92.905 us; speedup 1.0000x reference)
//
#include <hip/hip_runtime.h>
#include <math.h>

// Problem constants (from reference / setup_inputs)
#define N_ROIS   32
#define N_GT     (N_ROIS * 8)      // 256 context boxes
#define N_CAT    (N_ROIS * 9)      // 288 cat_rois rows
#define C_FEAT   256
#define H_FEAT   40
#define W_FEAT   40
#define P_FEAT   (H_FEAT * W_FEAT) // 1600 pixels
#define PH       7
#define PW       7
#define SCALE    0.0625f
#define MIN_SIZE 16.0f
#define CELLS    (PH * PW)                 // 49
#define POOL_PER_BOX (C_FEAT * CELLS)      // 12544
#define OUT_POOL_ELEMS ((size_t)N_CAT * POOL_PER_BOX)  // 3,612,672

#define N_TRANS_BLOCKS (P_FEAT / 32 * (C_FEAT / 32))   // 50*8 = 400
#define WIN 16   // static row window (covers boxes up to ~256 input px)

// ---------------------------------------------------------------------------
// Kernel 0 (fused prep): blocks 0..399 transpose features (C,P)->(P,C);
// block 400 computes context anchors + IoU labeling -> cat_rois (288x5).
// ---------------------------------------------------------------------------
__global__ void prep_kernel(const float* __restrict__ f,
                            const float* __restrict__ rois,
                            const int* __restrict__ hh_p,
                            const int* __restrict__ hw_p,
                            float* __restrict__ ft,
                            float* __restrict__ cat_out,
                            int use_transpose) {
    __shared__ float tile[32][33];   // transpose tile (+1 pad)
    __shared__ float R[N_ROIS * 5];  // rois stage for context half
    const int bid = blockIdx.x;
    const int tid = threadIdx.x;

    if (bid < N_TRANS_BLOCKS) {
        if (!use_transpose) return;
        const int pt = (bid % (P_FEAT / 32)) * 32;
        const int ct = (bid / (P_FEAT / 32)) * 32;
        const int lx = tid & 31;
        const int ly = tid >> 5;     // 0..7
        #pragma unroll
        for (int i = 0; i < 32; i += 8)
            tile[ly + i][lx] = f[(ct + ly + i) * P_FEAT + (pt + lx)];
        __syncthreads();
        #pragma unroll
        for (int i = 0; i < 32; i += 8)
            ft[(pt + ly + i) * C_FEAT + (ct + lx)] = tile[lx][ly + i];
        return;
    }

    // ---- context-anchor half (one block, 256 threads) ----
    if (tid < N_ROIS * 5) R[tid] = rois[tid];
    __syncthreads();

    const float hh = (float)(*hh_p);
    const float hw = (float)(*hw_p);

    const int g = tid;               // 0..255 -> gt box
    const int n = g >> 3;
    const int j = g & 7;
    const int m = (j < 4) ? j : j + 1;   // skip center of 3x3
    const int r  = m / 3;
    const int cc = m % 3;

    const float x1 = R[n * 5 + 1], y1 = R[n * 5 + 2];
    const float x2 = R[n * 5 + 3], y2 = R[n * 5 + 4];
    const float w = x2 - x1, h = y2 - y1;

    const float cx = x1 + w * ((float)cc - 0.5f);
    const float cy = y1 + h * ((float)r  - 0.5f);
    float bx1 = cx - w * 0.25f;
    float by1 = cy - h * 0.25f;
    float bx2 = cx + w * 0.25f;
    float by2 = cy + h * 0.25f;
    const float bw = bx2 - bx1 + 1.0f;
    const float bh = by2 - by1 + 1.0f;
    const bool invalid = (bx1 < 0.0f) || (by1 < 0.0f) ||
                         (bx2 >= hw) || (by2 >= hh) ||
                         (bw < MIN_SIZE) || (bh < MIN_SIZE);
    if (invalid) { bx1 = x1; by1 = y1; bx2 = x2; by2 = y2; }

    const float gw = bx2 - bx1 + 1.0f;
    const float gh = by2 - by1 + 1.0f;
    const float garea = gw * gh;
    const bool gdeg = (gw == 1.0f) && (gh == 1.0f);

    float best_ov = -INFINITY;
    int best = 0;
    for (int a = 0; a < N_ROIS; ++a) {
        const float ax1 = R[a * 5 + 1], ay1 = R[a * 5 + 2];
        const float ax2 = R[a * 5 + 3], ay2 = R[a * 5 + 4];
        const float aw = ax2 - ax1 + 1.0f, ah = ay2 - ay1 + 1.0f;
        float iw = fminf(ax2, bx2) - fmaxf(ax1, bx1) + 1.0f;
        float ih = fminf(ay2, by2) - fmaxf(ay1, by1) + 1.0f;
        iw = fmaxf(iw, 0.0f);
        ih = fmaxf(ih, 0.0f);
        const float inter = iw * ih;
        float ov = inter / (aw * ah + garea - inter);
        if (gdeg) ov = 0.0f;
        if (aw == 1.0f && ah == 1.0f) ov = -1.0f;
        if (ov > best_ov) { best_ov = ov; best = a; }
    }

    bool label = (best_ov >= 0.3f);
    const float w_cell = bx2 - bx1;
    const float h_cell = by2 - by1;
    const float rw = label ? (R[best * 5 + 3] - R[best * 5 + 1]) : 0.0f;
    const float rh = label ? (R[best * 5 + 4] - R[best * 5 + 2]) : 0.0f;
    label = label &&
            !(fmaxf(rw, rh) >= fmaxf(w_cell, h_cell)) &&
            !(fminf(rw, rh) < fminf(w_cell, h_cell) / 3.0f);
    if (label) {
        bx1 = R[best * 5 + 1]; by1 = R[best * 5 + 2];
        bx2 = R[best * 5 + 3]; by2 = R[best * 5 + 4];
    }

    float* row = cat_out + (size_t)(n * 9 + 1 + j) * 5;
    row[0] = 0.0f;
    row[1] = bx1; row[2] = by1; row[3] = bx2; row[4] = by2;
    if (j == 0) {
        float* rr = cat_out + (size_t)(n * 9) * 5;
        #pragma unroll
        for (int t = 0; t < 5; ++t) rr[t] = R[n * 5 + t];
    }
}

// ---------------------------------------------------------------------------
// Kernel 1: Caffe max RoIPool over transposed features (pixel-major,
// channel-minor). Block = (box, pooled-row i), thread = channel.
// Key: all cell bounds are block-uniform -> readfirstlane-scalarized so
// membership tests are s_cmp/s_cbranch; each feature row is register-cached
// in a static 16-wide window (16 independent batched loads) so there are
// no serialized dependent-load chains. Wide boxes (>16 cols) take a
// dynamic fallback loop (uniform branch; never taken for this data).
// ---------------------------------------------------------------------------
__global__ __launch_bounds__(256) void
roi_pool_kernel(const float* __restrict__ feat,
                const float* __restrict__ cat_rois,
                float* __restrict__ out) {
    const int b = blockIdx.x / PH;   // box 0..287
    const int i = blockIdx.x % PH;   // pooled row 0..6
    const int c = threadIdx.x;       // channel 0..255

    const float* cr = cat_rois + (size_t)b * 5;
    const float x1 = cr[1], y1 = cr[2], x2 = cr[3], y2 = cr[4];
    // jnp.round = round-half-to-even = rintf (default rounding mode)
    const float sw = rintf(x1 * SCALE);
    const float sh = rintf(y1 * SCALE);
    const float ew = rintf(x2 * SCALE);
    const float eh = rintf(y2 * SCALE);
    const float bsh = fmaxf(eh - sh + 1.0f, 1.0f) * (1.0f / (float)PH);
    const float bsw = fmaxf(ew - sw + 1.0f, 1.0f) * (1.0f / (float)PW);

    int hs = (int)fminf(fmaxf(floorf((float)i * bsh) + sh, 0.0f), (float)H_FEAT);
    int he = (int)fminf(fmaxf(ceilf((float)(i + 1) * bsh) + sh, 0.0f), (float)H_FEAT);

    int ws[PW], we[PW];
    #pragma unroll
    for (int j = 0; j < PW; ++j) {
        ws[j] = (int)fminf(fmaxf(floorf((float)j * bsw) + sw, 0.0f), (float)W_FEAT);
        we[j] = (int)fminf(fmaxf(ceilf((float)(j + 1) * bsw) + sw, 0.0f), (float)W_FEAT);
    }

    // All bounds are uniform across the block: pin them to SGPRs so the
    // compiler emits scalar compares/branches around the vector maxes.
    hs = __builtin_amdgcn_readfirstlane(hs);
    he = __builtin_amdgcn_readfirstlane(he);
    #pragma unroll
    for (int j = 0; j < PW; ++j) {
        ws[j] = __builtin_amdgcn_readfirstlane(ws[j]);
        we[j] = __builtin_amdgcn_readfirstlane(we[j]);
    }
    const int xs = ws[0];                 // window start (clamped >= 0)
    const bool wide = (we[PW - 1] > xs + WIN);  // uniform; false for this data

    float mx[PW];
    #pragma unroll
    for (int j = 0; j < PW; ++j) mx[j] = -1e30f;

    for (int y = hs; y < he; ++y) {
        const float* fr = feat + (size_t)(y * W_FEAT) * C_FEAT + c;
        // static batched window load: 16 independent 256B wave-loads
        float win[WIN];
        #pragma unroll
        for (int k = 0; k < WIN; ++k) {
            int x = xs + k;
            x = (x < W_FEAT - 1) ? x : (W_FEAT - 1);  // clamp addr; guarded by we[j]<=40 on use
            win[k] = fr[(size_t)x * C_FEAT];
        }
        #pragma unroll
        for (int j = 0; j < PW; ++j) {
            #pragma unroll
            for (int k = 0; k < WIN; ++k) {
                const int x = xs + k;
                if (x >= ws[j] && x < we[j])   // scalar test -> s_cbranch
                    mx[j] = fmaxf(mx[j], win[k]);
            }
        }
        if (wide) {  // general-correctness fallback, uniform, normally skipped
            #pragma unroll
            for (int j = 0; j < PW; ++j) {
                int x0 = (ws[j] > xs + WIN) ? ws[j] : (xs + WIN);
                for (int x = x0; x < we[j]; ++x)
                    mx[j] = fmaxf(mx[j], fr[(size_t)x * C_FEAT]);
            }
        }
    }

    const bool rowv = (he > hs);
    float* ob = out + (size_t)b * POOL_PER_BOX + (size_t)c * CELLS + i * PW;
    #pragma unroll
    for (int j = 0; j < PW; ++j)
        ob[j] = (rowv && (we[j] > ws[j])) ? mx[j] : 0.0f;
}

// fallback pool (untransposed layout) — only used if ws too small
__global__ __launch_bounds__(256) void
roi_pool_kernel_nchw(const float* __restrict__ feat,
                     const float* __restrict__ cat_rois,
                     float* __restrict__ out) {
    const int b = blockIdx.x / PH;
    const int i = blockIdx.x % PH;
    const int c = threadIdx.x;

    const float* cr = cat_rois + (size_t)b * 5;
    const float sw = rintf(cr[1] * SCALE);
    const float sh = rintf(cr[2] * SCALE);
    const float ew = rintf(cr[3] * SCALE);
    const float eh = rintf(cr[4] * SCALE);
    const float bsh = fmaxf(eh - sh + 1.0f, 1.0f) * (1.0f / (float)PH);
    const float bsw = fmaxf(ew - sw + 1.0f, 1.0f) * (1.0f / (float)PW);

    const int hs = (int)fminf(fmaxf(floorf((float)i * bsh) + sh, 0.0f), (float)H_FEAT);
    const int he = (int)fminf(fmaxf(ceilf((float)(i + 1) * bsh) + sh, 0.0f), (float)H_FEAT);
    int ws[PW], we[PW];
    #pragma unroll
    for (int j = 0; j < PW; ++j) {
        ws[j] = (int)fminf(fmaxf(floorf((float)j * bsw) + sw, 0.0f), (float)W_FEAT);
        we[j] = (int)fminf(fmaxf(ceilf((float)(j + 1) * bsw) + sw, 0.0f), (float)W_FEAT);
    }
    float mx[PW];
    #pragma unroll
    for (int j = 0; j < PW; ++j) mx[j] = -1e30f;
    for (int y = hs; y < he; ++y) {
        const float* fr = feat + (size_t)c * P_FEAT + y * W_FEAT;
        #pragma unroll
        for (int j = 0; j < PW; ++j)
            for (int x = ws[j]; x < we[j]; ++x)
                mx[j] = fmaxf(mx[j], fr[x]);
    }
    const bool rowv = (he > hs);
    float* ob = out + (size_t)b * POOL_PER_BOX + (size_t)c * CELLS + i * PW;
    #pragma unroll
    for (int j = 0; j < PW; ++j)
        ob[j] = (rowv && (we[j] > ws[j])) ? mx[j] : 0.0f;
}

// ---------------------------------------------------------------------------
extern "C" void kernel_launch(void* const* d_in, const int* in_sizes, int n_in,
                              void* d_out, int out_size, void* d_ws, size_t ws_size,
                              hipStream_t stream) {
    const float* features = (const float*)d_in[0];   // (1,256,40,40)
    const float* rois     = (const float*)d_in[1];   // (32,5)
    const int*   hh_p     = (const int*)d_in[2];
    const int*   hw_p     = (const int*)d_in[3];

    float* out      = (float*)d_out;
    float* cat_out  = out + OUT_POOL_ELEMS;          // (288,5) tail of d_out
    float* ft       = (float*)d_ws;                  // transposed features

    const size_t ft_bytes = (size_t)C_FEAT * P_FEAT * sizeof(float);
    const int use_transpose = (ws_size >= ft_bytes) ? 1 : 0;

    hipLaunchKernelGGL(prep_kernel, dim3(N_TRANS_BLOCKS + 1), dim3(256), 0, stream,
                       features, rois, hh_p, hw_p, ft, cat_out, use_transpose);

    if (use_transpose) {
        hipLaunchKernelGGL(roi_pool_kernel, dim3(N_CAT * PH), dim3(C_FEAT), 0, stream,
                           ft, cat_out, out);
    } else {
        hipLaunchKernelGGL(roi_pool_kernel_nchw, dim3(N_CAT * PH), dim3(C_FEAT), 0, stream,
                           features, cat_out, out);
    }
}

// Round 4
// 82.423 us; speedup vs baseline: 1.1272x; 1.1272x over previous
//
#include <hip/hip_runtime.h>
#include <math.h>

// Problem constants (from reference / setup_inputs)
#define N_ROIS   32
#define N_CAT    (N_ROIS * 9)      // 288 cat_rois rows
#define C_FEAT   256
#define H_FEAT   40
#define W_FEAT   40
#define P_FEAT   (H_FEAT * W_FEAT) // 1600 pixels
#define PH       7
#define PW       7
#define SCALE    0.0625f
#define MIN_SIZE 16.0f
#define CELLS    (PH * PW)                 // 49
#define POOL_PER_BOX (C_FEAT * CELLS)      // 12544
#define OUT_POOL_ELEMS ((size_t)N_CAT * POOL_PER_BOX)  // 3,612,672

#define N_TRANS_BLOCKS (P_FEAT / 32 * (C_FEAT / 32))   // 50*8 = 400
#define WIN 14   // static row window: bsw<=2 -> box spans <=14 feature cols

// ---------------------------------------------------------------------------
// Kernel 0 (fused prep): blocks 0..399 transpose features (C,P)->(P,C);
// block 400 computes context anchors + IoU labeling -> cat_rois (288x5).
// ---------------------------------------------------------------------------
__global__ void prep_kernel(const float* __restrict__ f,
                            const float* __restrict__ rois,
                            const int* __restrict__ hh_p,
                            const int* __restrict__ hw_p,
                            float* __restrict__ ft,
                            float* __restrict__ cat_out,
                            int use_transpose) {
    __shared__ float tile[32][33];   // transpose tile (+1 pad)
    __shared__ float R[N_ROIS * 5];  // rois stage for context half
    const int bid = blockIdx.x;
    const int tid = threadIdx.x;

    if (bid < N_TRANS_BLOCKS) {
        if (!use_transpose) return;
        const int pt = (bid % (P_FEAT / 32)) * 32;
        const int ct = (bid / (P_FEAT / 32)) * 32;
        const int lx = tid & 31;
        const int ly = tid >> 5;     // 0..7
        #pragma unroll
        for (int i = 0; i < 32; i += 8)
            tile[ly + i][lx] = f[(ct + ly + i) * P_FEAT + (pt + lx)];
        __syncthreads();
        #pragma unroll
        for (int i = 0; i < 32; i += 8)
            ft[(pt + ly + i) * C_FEAT + (ct + lx)] = tile[lx][ly + i];
        return;
    }

    // ---- context-anchor half (one block, 256 threads) ----
    if (tid < N_ROIS * 5) R[tid] = rois[tid];
    __syncthreads();

    const float hh = (float)(*hh_p);
    const float hw = (float)(*hw_p);

    const int g = tid;               // 0..255 -> gt box
    const int n = g >> 3;
    const int j = g & 7;
    const int m = (j < 4) ? j : j + 1;   // skip center of 3x3
    const int r  = m / 3;
    const int cc = m % 3;

    const float x1 = R[n * 5 + 1], y1 = R[n * 5 + 2];
    const float x2 = R[n * 5 + 3], y2 = R[n * 5 + 4];
    const float w = x2 - x1, h = y2 - y1;

    const float cx = x1 + w * ((float)cc - 0.5f);
    const float cy = y1 + h * ((float)r  - 0.5f);
    float bx1 = cx - w * 0.25f;
    float by1 = cy - h * 0.25f;
    float bx2 = cx + w * 0.25f;
    float by2 = cy + h * 0.25f;
    const float bw = bx2 - bx1 + 1.0f;
    const float bh = by2 - by1 + 1.0f;
    const bool invalid = (bx1 < 0.0f) || (by1 < 0.0f) ||
                         (bx2 >= hw) || (by2 >= hh) ||
                         (bw < MIN_SIZE) || (bh < MIN_SIZE);
    if (invalid) { bx1 = x1; by1 = y1; bx2 = x2; by2 = y2; }

    const float gw = bx2 - bx1 + 1.0f;
    const float gh = by2 - by1 + 1.0f;
    const float garea = gw * gh;
    const bool gdeg = (gw == 1.0f) && (gh == 1.0f);

    float best_ov = -INFINITY;
    int best = 0;
    for (int a = 0; a < N_ROIS; ++a) {
        const float ax1 = R[a * 5 + 1], ay1 = R[a * 5 + 2];
        const float ax2 = R[a * 5 + 3], ay2 = R[a * 5 + 4];
        const float aw = ax2 - ax1 + 1.0f, ah = ay2 - ay1 + 1.0f;
        float iw = fminf(ax2, bx2) - fmaxf(ax1, bx1) + 1.0f;
        float ih = fminf(ay2, by2) - fmaxf(ay1, by1) + 1.0f;
        iw = fmaxf(iw, 0.0f);
        ih = fmaxf(ih, 0.0f);
        const float inter = iw * ih;
        float ov = inter / (aw * ah + garea - inter);
        if (gdeg) ov = 0.0f;
        if (aw == 1.0f && ah == 1.0f) ov = -1.0f;
        if (ov > best_ov) { best_ov = ov; best = a; }
    }

    bool label = (best_ov >= 0.3f);
    const float w_cell = bx2 - bx1;
    const float h_cell = by2 - by1;
    const float rw = label ? (R[best * 5 + 3] - R[best * 5 + 1]) : 0.0f;
    const float rh = label ? (R[best * 5 + 4] - R[best * 5 + 2]) : 0.0f;
    label = label &&
            !(fmaxf(rw, rh) >= fmaxf(w_cell, h_cell)) &&
            !(fminf(rw, rh) < fminf(w_cell, h_cell) / 3.0f);
    if (label) {
        bx1 = R[best * 5 + 1]; by1 = R[best * 5 + 2];
        bx2 = R[best * 5 + 3]; by2 = R[best * 5 + 4];
    }

    float* row = cat_out + (size_t)(n * 9 + 1 + j) * 5;
    row[0] = 0.0f;
    row[1] = bx1; row[2] = by1; row[3] = bx2; row[4] = by2;
    if (j == 0) {
        float* rr = cat_out + (size_t)(n * 9) * 5;
        #pragma unroll
        for (int t = 0; t < 5; ++t) rr[t] = R[n * 5 + t];
    }
}

// ---------------------------------------------------------------------------
// Kernel 1: Caffe max RoIPool over transposed features (pixel-major,
// channel-minor). Block = (pooled-row i, box b) with blockIdx = i*288+b:
// 288 % 8 == 0 -> all 7 row-blocks of box b land on XCD b%8, so their
// interleaved 28B output chunks merge into full cache lines in ONE L2
// (write combining) and ft reads for a box stay L2-local.
// Inner loop: 14 batched INDEPENDENT window loads per y, then branch-free
// VALU-predicated maxes; cell j only tests k < 2j+2 (valid for bsw<=2),
// halving predicate work. General boxes (bsw>2) take a dynamic fallback.
// ---------------------------------------------------------------------------
__global__ __launch_bounds__(256) void
roi_pool_kernel(const float* __restrict__ feat,
                const float* __restrict__ cat_rois,
                float* __restrict__ out) {
    const int i = blockIdx.x / N_CAT;  // pooled row 0..6 (slow index)
    const int b = blockIdx.x % N_CAT;  // box 0..287     (fast -> XCD = b%8)
    const int c = threadIdx.x;         // channel 0..255

    const float* cr = cat_rois + (size_t)b * 5;
    const float x1 = cr[1], y1 = cr[2], x2 = cr[3], y2 = cr[4];
    // jnp.round = round-half-to-even = rintf (default rounding mode)
    const float sw = rintf(x1 * SCALE);
    const float sh = rintf(y1 * SCALE);
    const float ew = rintf(x2 * SCALE);
    const float eh = rintf(y2 * SCALE);
    const float bsh = fmaxf(eh - sh + 1.0f, 1.0f) * (1.0f / (float)PH);
    const float bsw = fmaxf(ew - sw + 1.0f, 1.0f) * (1.0f / (float)PW);

    const int hs = (int)fminf(fmaxf(floorf((float)i * bsh) + sh, 0.0f), (float)H_FEAT);
    const int he = (int)fminf(fmaxf(ceilf((float)(i + 1) * bsh) + sh, 0.0f), (float)H_FEAT);

    int ws[PW], we[PW];
    #pragma unroll
    for (int j = 0; j < PW; ++j) {
        ws[j] = (int)fminf(fmaxf(floorf((float)j * bsw) + sw, 0.0f), (float)W_FEAT);
        we[j] = (int)fminf(fmaxf(ceilf((float)(j + 1) * bsw) + sw, 0.0f), (float)W_FEAT);
    }

    const int xs = ws[0];              // window start (>=0 for this data)
    const bool narrow = (bsw <= 2.0f); // guarantees span<=14 and we[j]<=xs+2j+2

    float mx[PW];
    #pragma unroll
    for (int j = 0; j < PW; ++j) mx[j] = -1e30f;

    if (narrow) {
        for (int y = hs; y < he; ++y) {
            const float* fr = feat + (size_t)(y * W_FEAT) * C_FEAT + c;
            // 14 independent batched loads (one vmcnt group, no serial chains)
            float win[WIN];
            #pragma unroll
            for (int k = 0; k < WIN; ++k) {
                int x = xs + k;
                x = (x < W_FEAT - 1) ? x : (W_FEAT - 1);  // clamp addr; unused if OOB
                win[k] = fr[(size_t)x * C_FEAT];
            }
            #pragma unroll
            for (int j = 0; j < PW; ++j) {
                const int lo = ws[j], hi = we[j];
                const int kmax = (2 * j + 2 < WIN) ? (2 * j + 2) : WIN;
                #pragma unroll
                for (int k = 0; k < kmax; ++k) {
                    const int x = xs + k;
                    const bool in = (x >= lo) & (x < hi);
                    const float t = fmaxf(mx[j], win[k]);
                    mx[j] = in ? t : mx[j];      // v_cndmask, no branch
                }
            }
        }
    } else {
        // general fallback (not taken for this data): dynamic loops
        for (int y = hs; y < he; ++y) {
            const float* fr = feat + (size_t)(y * W_FEAT) * C_FEAT + c;
            #pragma unroll
            for (int j = 0; j < PW; ++j)
                for (int x = ws[j]; x < we[j]; ++x)
                    mx[j] = fmaxf(mx[j], fr[(size_t)x * C_FEAT]);
        }
    }

    const bool rowv = (he > hs);
    float* ob = out + (size_t)b * POOL_PER_BOX + (size_t)c * CELLS + i * PW;
    #pragma unroll
    for (int j = 0; j < PW; ++j)
        ob[j] = (rowv && (we[j] > ws[j])) ? mx[j] : 0.0f;
}

// fallback pool (untransposed layout) — only used if ws too small
__global__ __launch_bounds__(256) void
roi_pool_kernel_nchw(const float* __restrict__ feat,
                     const float* __restrict__ cat_rois,
                     float* __restrict__ out) {
    const int i = blockIdx.x / N_CAT;
    const int b = blockIdx.x % N_CAT;
    const int c = threadIdx.x;

    const float* cr = cat_rois + (size_t)b * 5;
    const float sw = rintf(cr[1] * SCALE);
    const float sh = rintf(cr[2] * SCALE);
    const float ew = rintf(cr[3] * SCALE);
    const float eh = rintf(cr[4] * SCALE);
    const float bsh = fmaxf(eh - sh + 1.0f, 1.0f) * (1.0f / (float)PH);
    const float bsw = fmaxf(ew - sw + 1.0f, 1.0f) * (1.0f / (float)PW);

    const int hs = (int)fminf(fmaxf(floorf((float)i * bsh) + sh, 0.0f), (float)H_FEAT);
    const int he = (int)fminf(fmaxf(ceilf((float)(i + 1) * bsh) + sh, 0.0f), (float)H_FEAT);
    int ws[PW], we[PW];
    #pragma unroll
    for (int j = 0; j < PW; ++j) {
        ws[j] = (int)fminf(fmaxf(floorf((float)j * bsw) + sw, 0.0f), (float)W_FEAT);
        we[j] = (int)fminf(fmaxf(ceilf((float)(j + 1) * bsw) + sw, 0.0f), (float)W_FEAT);
    }
    float mx[PW];
    #pragma unroll
    for (int j = 0; j < PW; ++j) mx[j] = -1e30f;
    for (int y = hs; y < he; ++y) {
        const float* fr = feat + (size_t)c * P_FEAT + y * W_FEAT;
        #pragma unroll
        for (int j = 0; j < PW; ++j)
            for (int x = ws[j]; x < we[j]; ++x)
                mx[j] = fmaxf(mx[j], fr[x]);
    }
    const bool rowv = (he > hs);
    float* ob = out + (size_t)b * POOL_PER_BOX + (size_t)c * CELLS + i * PW;
    #pragma unroll
    for (int j = 0; j < PW; ++j)
        ob[j] = (rowv && (we[j] > ws[j])) ? mx[j] : 0.0f;
}

// ---------------------------------------------------------------------------
extern "C" void kernel_launch(void* const* d_in, const int* in_sizes, int n_in,
                              void* d_out, int out_size, void* d_ws, size_t ws_size,
                              hipStream_t stream) {
    const float* features = (const float*)d_in[0];   // (1,256,40,40)
    const float* rois     = (const float*)d_in[1];   // (32,5)
    const int*   hh_p     = (const int*)d_in[2];
    const int*   hw_p     = (const int*)d_in[3];

    float* out      = (float*)d_out;
    float* cat_out  = out + OUT_POOL_ELEMS;          // (288,5) tail of d_out
    float* ft       = (float*)d_ws;                  // transposed features

    const size_t ft_bytes = (size_t)C_FEAT * P_FEAT * sizeof(float);
    const int use_transpose = (ws_size >= ft_bytes) ? 1 : 0;

    hipLaunchKernelGGL(prep_kernel, dim3(N_TRANS_BLOCKS + 1), dim3(256), 0, stream,
                       features, rois, hh_p, hw_p, ft, cat_out, use_transpose);

    if (use_transpose) {
        hipLaunchKernelGGL(roi_pool_kernel, dim3(PH * N_CAT), dim3(C_FEAT), 0, stream,
                           ft, cat_out, out);
    } else {
        hipLaunchKernelGGL(roi_pool_kernel_nchw, dim3(PH * N_CAT), dim3(C_FEAT), 0, stream,
                           features, cat_out, out);
    }
}